// Round 9
// baseline (221.299 us; speedup 1.0000x reference)
//
#include <hip/hip_runtime.h>

// Elementwise 16-step spike recurrence:
//   v=|x|; z=0; o=0;
//   for t: v -= z*h[t]; z = (v > T[t]); o += z*d[t];
//   out = o * sign(x)
// (v-T)/(|v|+1) > 0  <=>  v > T, so the divide is eliminated. z in {0,1}
// makes z*h and z*d exact products -> bit-exact (verified rounds 1,3-8).
// Step 0 folded: T[0] < 0 <= |x| => z=1, o=d[0], v unchanged (exact).
//
// Round-9: max-occupancy fine-grained variant. 1 float4/thread (131072
// blocks), VGPR ~32 (safely under the 64-VGPR occupancy cliff -> 8
// waves/SIMD), so the CU scheduler interleaves many small load->compute->
// store lifecycles instead of few big ones. Keeps: s_load coefficients,
// pk_fma with SGPR-fed coefficient pairs, cached loads (L3 serves ~50% of
// input), NT stores (preserve input L3 residency).

typedef float f32x2 __attribute__((ext_vector_type(2)));
typedef float f32x4 __attribute__((ext_vector_type(4)));

// r = z*c + acc, 2 lanes/inst; c comes straight from SGPRs (wave-uniform).
__device__ __forceinline__ f32x2 pk_fma_s(f32x2 z, f32x2 c_sgpr, f32x2 acc) {
    f32x2 r;
    asm("v_pk_fma_f32 %0, %1, %2, %3" : "=v"(r) : "v"(z), "s"(c_sgpr), "v"(acc));
    return r;
}

__device__ __forceinline__ float spike_elem(float xj, const float* nh,
                                            const float* dd, const float* TT) {
    float v = fabsf(xj);
    float z = 1.0f;       // step 0 folded
    float o = dd[0];
#pragma unroll
    for (int t = 1; t < 16; ++t) {
        v = fmaf(z, nh[t], v);
        z = (v > TT[t]) ? 1.0f : 0.0f;
        o = fmaf(z, dd[t], o);
    }
    o = copysignf(o, xj);
    return (xj == 0.0f) ? 0.0f : o;
}

__global__ __launch_bounds__(256) void spike_scan_kernel(
    const float* __restrict__ x,
    const float* __restrict__ h,
    const float* __restrict__ d,
    const float* __restrict__ T,
    float* __restrict__ out,
    long long n4, long long n)
{
    // Plain uniform reads -> s_load, coefficients live in SGPRs.
    float nh[16], dd[16], TT[16];
#pragma unroll
    for (int t = 0; t < 16; ++t) {
        nh[t] = -h[t];
        dd[t] = d[t];
        TT[t] = T[t];
    }

    const long long i = (long long)blockIdx.x * blockDim.x + threadIdx.x;

    if (i < n4) {
        const f32x4* __restrict__ x4 = reinterpret_cast<const f32x4*>(x);
        f32x4* __restrict__ o4 = reinterpret_cast<f32x4*>(out);

        f32x4 a = x4[i];          // cached: L3 serves the resident half

        // 2 packed chains of 2 elements each.
        f32x2 v2[2], z2[2], o2[2];
#pragma unroll
        for (int k = 0; k < 2; ++k) {
            v2[k][0] = fabsf(a[2 * k]);
            v2[k][1] = fabsf(a[2 * k + 1]);
            z2[k][0] = 1.0f; z2[k][1] = 1.0f;   // step 0 folded
            o2[k][0] = dd[0]; o2[k][1] = dd[0];
        }

#pragma unroll
        for (int t = 1; t < 16; ++t) {
            const f32x2 nhp = {nh[t], nh[t]};   // SGPR pair (uniform)
            const f32x2 ddp = {dd[t], dd[t]};
#pragma unroll
            for (int k = 0; k < 2; ++k)
                v2[k] = pk_fma_s(z2[k], nhp, v2[k]);
#pragma unroll
            for (int k = 0; k < 2; ++k) {
                z2[k][0] = (v2[k][0] > TT[t]) ? 1.0f : 0.0f;
                z2[k][1] = (v2[k][1] > TT[t]) ? 1.0f : 0.0f;
            }
#pragma unroll
            for (int k = 0; k < 2; ++k)
                o2[k] = pk_fma_s(z2[k], ddp, o2[k]);
        }

        f32x4 r;
#pragma unroll
        for (int j = 0; j < 4; ++j) {
            const float oj = o2[j / 2][j & 1];
            r[j] = (a[j] == 0.0f) ? 0.0f : copysignf(oj, a[j]);
        }
        __builtin_nontemporal_store(r, &o4[i]);
    }

    // Scalar tail [4*n4, n) — block 0 only. (Empty: n = 2^27.)
    if (blockIdx.x == 0) {
        for (long long k = 4 * n4 + threadIdx.x; k < n; k += blockDim.x) {
            out[k] = spike_elem(x[k], nh, dd, TT);
        }
    }
}

extern "C" void kernel_launch(void* const* d_in, const int* in_sizes, int n_in,
                              void* d_out, int out_size, void* d_ws, size_t ws_size,
                              hipStream_t stream) {
    const float* x = (const float*)d_in[0];
    const float* h = (const float*)d_in[1];
    const float* d = (const float*)d_in[2];
    const float* T = (const float*)d_in[3];
    float* out = (float*)d_out;

    const long long n = (long long)out_size;
    const long long n4 = n / 4;

    const int block = 256;
    long long grid_ll = (n4 + block - 1) / block;  // exact cover: 1 float4/thread
    if (grid_ll < 1) grid_ll = 1;
    const int grid = (int)grid_ll;

    spike_scan_kernel<<<grid, block, 0, stream>>>(x, h, d, T, out, n4, n);
}

// Round 10
// 201.007 us; speedup vs baseline: 1.1010x; 1.1010x over previous
//
#include <hip/hip_runtime.h>

// Elementwise 16-step spike recurrence:
//   v=|x|; z=0; o=0;
//   for t: v -= z*h[t]; z = (v > T[t]); o += z*d[t];
//   out = o * sign(x)
// (v-T)/(|v|+1) > 0  <=>  v > T, so the divide is eliminated. z in {0,1}
// makes z*h and z*d exact products -> bit-exact (verified rounds 1,3-9).
// Step 0 folded: T[0] < 0 <= |x| => z=1, o=d[0], v unchanged (exact).
//
// Round-10: 16 elems/thread (4 float4 tiles; granularity curve says coarser
// wins: 4/thread=221us, 8/thread=199.8us) with register-compressed epilogue:
// precompute s = sign(x) in {-1,0,1} packed as f32x2 pairs (8 regs for 16
// elems instead of 16 regs of x), finish with v_pk_mul_f32(o2,s2) — exactly
// the reference's "out * signs" arithmetic (o*(+-1), o*0 exact -> bit-exact).
// Keeps: s_load SGPR coefficients, pk_fma with SGPR-fed coefficient pairs,
// cached loads (L3 serves ~half the input), NT stores.

typedef float f32x2 __attribute__((ext_vector_type(2)));
typedef float f32x4 __attribute__((ext_vector_type(4)));

// r = z*c + acc, 2 lanes/inst; c comes straight from SGPRs (wave-uniform).
__device__ __forceinline__ f32x2 pk_fma_s(f32x2 z, f32x2 c_sgpr, f32x2 acc) {
    f32x2 r;
    asm("v_pk_fma_f32 %0, %1, %2, %3" : "=v"(r) : "v"(z), "s"(c_sgpr), "v"(acc));
    return r;
}

__device__ __forceinline__ f32x2 pk_mul(f32x2 a, f32x2 b) {
    f32x2 r;
    asm("v_pk_mul_f32 %0, %1, %2" : "=v"(r) : "v"(a), "v"(b));
    return r;
}

__device__ __forceinline__ float spike_elem(float xj, const float* nh,
                                            const float* dd, const float* TT) {
    float v = fabsf(xj);
    float z = 1.0f;       // step 0 folded
    float o = dd[0];
#pragma unroll
    for (int t = 1; t < 16; ++t) {
        v = fmaf(z, nh[t], v);
        z = (v > TT[t]) ? 1.0f : 0.0f;
        o = fmaf(z, dd[t], o);
    }
    o = copysignf(o, xj);
    return (xj == 0.0f) ? 0.0f : o;
}

__global__ __launch_bounds__(256) void spike_scan_kernel(
    const float* __restrict__ x,
    const float* __restrict__ h,
    const float* __restrict__ d,
    const float* __restrict__ T,
    float* __restrict__ out,
    long long H,          // n4/4: tile stride (4 tiles/thread)
    long long n4, long long n)
{
    // Plain uniform reads -> s_load, coefficients live in SGPRs.
    float nh[16], dd[16], TT[16];
#pragma unroll
    for (int t = 0; t < 16; ++t) {
        nh[t] = -h[t];
        dd[t] = d[t];
        TT[t] = T[t];
    }

    const long long i = (long long)blockIdx.x * blockDim.x + threadIdx.x;

    if (i < H) {
        const f32x4* __restrict__ x4 = reinterpret_cast<const f32x4*>(x);
        f32x4* __restrict__ o4 = reinterpret_cast<f32x4*>(out);

        // 4 independent 16B loads in flight.
        f32x4 t0 = x4[i];
        f32x4 t1 = x4[i + H];
        f32x4 t2 = x4[i + 2 * H];
        f32x4 t3 = x4[i + 3 * H];

        // 8 packed chains of 2 elements. x is NOT kept live: only
        // s = sign(x) in {-1,0,+1} (pairs) survives to the epilogue.
        f32x2 v2[8], z2[8], o2[8], s2[8];
        float xe[16];
#pragma unroll
        for (int j = 0; j < 4; ++j) {
            xe[j]      = t0[j];
            xe[4 + j]  = t1[j];
            xe[8 + j]  = t2[j];
            xe[12 + j] = t3[j];
        }
#pragma unroll
        for (int k = 0; k < 8; ++k) {
#pragma unroll
            for (int l = 0; l < 2; ++l) {
                const float xv = xe[2 * k + l];
                v2[k][l] = fabsf(xv);
                const float pm1 = __int_as_float(
                    (__float_as_int(xv) & 0x80000000) | 0x3f800000);
                s2[k][l] = (xv == 0.0f) ? 0.0f : pm1;   // sign(x)
                z2[k][l] = 1.0f;                        // step 0 folded
                o2[k][l] = dd[0];
            }
        }

#pragma unroll
        for (int t = 1; t < 16; ++t) {
            const f32x2 nhp = {nh[t], nh[t]};   // SGPR pair (uniform)
            const f32x2 ddp = {dd[t], dd[t]};
#pragma unroll
            for (int k = 0; k < 8; ++k)
                v2[k] = pk_fma_s(z2[k], nhp, v2[k]);
#pragma unroll
            for (int k = 0; k < 8; ++k) {
                z2[k][0] = (v2[k][0] > TT[t]) ? 1.0f : 0.0f;
                z2[k][1] = (v2[k][1] > TT[t]) ? 1.0f : 0.0f;
            }
#pragma unroll
            for (int k = 0; k < 8; ++k)
                o2[k] = pk_fma_s(z2[k], ddp, o2[k]);
        }

        // Epilogue: out = o * sign(x) — the reference's exact arithmetic.
#pragma unroll
        for (int k = 0; k < 8; ++k) o2[k] = pk_mul(o2[k], s2[k]);

        f32x4 r0, r1, r2, r3;
#pragma unroll
        for (int j = 0; j < 4; ++j) {
            r0[j] = o2[j / 2][j & 1];
            r1[j] = o2[2 + j / 2][j & 1];
            r2[j] = o2[4 + j / 2][j & 1];
            r3[j] = o2[6 + j / 2][j & 1];
        }
        __builtin_nontemporal_store(r0, &o4[i]);
        __builtin_nontemporal_store(r1, &o4[i + H]);
        __builtin_nontemporal_store(r2, &o4[i + 2 * H]);
        __builtin_nontemporal_store(r3, &o4[i + 3 * H]);
    }

    // Leftovers: float4 tiles in [4H, n4) plus scalar tail [4*n4, n).
    // (Both empty for the real shape: n = 2^27.)
    if (blockIdx.x == 0) {
        const f32x4* __restrict__ x4 = reinterpret_cast<const f32x4*>(x);
        f32x4* __restrict__ o4 = reinterpret_cast<f32x4*>(out);
        for (long long j = 4 * H + threadIdx.x; j < n4; j += blockDim.x) {
            f32x4 a = x4[j];
            f32x4 r;
#pragma unroll
            for (int q = 0; q < 4; ++q) r[q] = spike_elem(a[q], nh, dd, TT);
            __builtin_nontemporal_store(r, &o4[j]);
        }
        for (long long k = 4 * n4 + threadIdx.x; k < n; k += blockDim.x) {
            out[k] = spike_elem(x[k], nh, dd, TT);
        }
    }
}

extern "C" void kernel_launch(void* const* d_in, const int* in_sizes, int n_in,
                              void* d_out, int out_size, void* d_ws, size_t ws_size,
                              hipStream_t stream) {
    const float* x = (const float*)d_in[0];
    const float* h = (const float*)d_in[1];
    const float* d = (const float*)d_in[2];
    const float* T = (const float*)d_in[3];
    float* out = (float*)d_out;

    const long long n = (long long)out_size;
    const long long n4 = n / 4;
    const long long H = n4 / 4;   // 4 float4 tiles per thread

    const int block = 256;
    long long grid_ll = (H + block - 1) / block;  // exact cover
    if (grid_ll < 1) grid_ll = 1;
    const int grid = (int)grid_ll;

    spike_scan_kernel<<<grid, block, 0, stream>>>(x, h, d, T, out, H, n4, n);
}